// Round 15
// baseline (2889.192 us; speedup 1.0000x reference)
//
#include <hip/hip_runtime.h>
#include <cmath>

#define B_   128
#define T_   100
#define IN_  512
#define H_   1024
#define E_   8
#define HH_  512
#define GIN_ 5
#define GH_  8

// ---- tierS LDS: A-lo KT0..79 = 80KB | B dbuf 2 x 32KB (also 64KB dump) ----
#define ALO_   0
#define BOFF_  81920
#define LDSZ5  147456
// ---- r10 fallback LDS layout
#define A_LOF 49152
#define BB_HI 98304
#define BB_LO 114688
#define LDSZF 131072

typedef unsigned long long u64t;
typedef unsigned int uint32;
typedef __attribute__((ext_vector_type(8)))  short bf16x8;
typedef __attribute__((ext_vector_type(4)))  float f32x4;
typedef __attribute__((ext_vector_type(16))) float f32x16;

__device__ __forceinline__ float sigf(float x) { return 1.0f / (1.0f + expf(-x)); }

__device__ __forceinline__ float4 ld_h4_sc1(const float4* p) {
  const u64t* q = (const u64t*)p;
  u64t a = __hip_atomic_load(q,     __ATOMIC_RELAXED, __HIP_MEMORY_SCOPE_AGENT);
  u64t b = __hip_atomic_load(q + 1, __ATOMIC_RELAXED, __HIP_MEMORY_SCOPE_AGENT);
  union { u64t u; float2 f; } ca, cb;
  ca.u = a; cb.u = b;
  return make_float4(ca.f.x, ca.f.y, cb.f.x, cb.f.y);
}

__device__ __forceinline__ void st_u64_sc1(void* p, u64t v) {
  __hip_atomic_store((u64t*)p, v, __ATOMIC_RELAXED, __HIP_MEMORY_SCOPE_AGENT);
}

__device__ __forceinline__ void gridbar(unsigned* c) {
  __syncthreads();
  if (threadIdx.x == 0) {
    __hip_atomic_fetch_add(c, 1u, __ATOMIC_RELEASE, __HIP_MEMORY_SCOPE_AGENT);
    while (__hip_atomic_load(c, __ATOMIC_RELAXED, __HIP_MEMORY_SCOPE_AGENT) < gridDim.x) {
      __builtin_amdgcn_s_sleep(1);
    }
  }
  __syncthreads();
}

__device__ __forceinline__ uint32 bf16_rne(float f) {
  uint32 u = __builtin_bit_cast(uint32, f);
  return (u + 0x7FFFu + ((u >> 16) & 1u)) >> 16;
}

__device__ __forceinline__ void split2(float f0, float f1, uint32& h, uint32& l) {
  uint32 h0 = bf16_rne(f0), h1 = bf16_rne(f1);
  float hf0 = __builtin_bit_cast(float, h0 << 16);
  float hf1 = __builtin_bit_cast(float, h1 << 16);
  uint32 l0 = bf16_rne(f0 - hf0), l1 = bf16_rne(f1 - hf1);
  h = h0 | (h1 << 16);
  l = l0 | (l1 << 16);
}

__device__ __forceinline__ void gl_lds16(const char* g, char* l) {
  __builtin_amdgcn_global_load_lds(
      (const __attribute__((address_space(1))) uint32*)(const void*)g,
      (__attribute__((address_space(3))) uint32*)(void*)l, 16, 0, 0);
}

// ---- one-shot: X -> bf16 hi/lo planes, 32-col B-frag layout for 32x32x16
__global__ __launch_bounds__(256) void xsplit_kernel(
    const float* __restrict__ X, char* __restrict__ xpl)
{
  int idx  = blockIdx.x * 256 + threadIdx.x;   // < 819200
  int lane = idx & 63;
  int bq   = (idx >> 6) & 3;
  int KT   = (idx >> 8) & 31;
  int t    = idx >> 13;
  int col  = lane & 31, kg = lane >> 5;
  int b    = bq * 32 + col;
  int k    = KT * 16 + kg * 8;
  const float* src = X + ((size_t)b * T_ + t) * IN_ + k;
  float4 va = *(const float4*)src;
  float4 vb = *(const float4*)(src + 4);
  uint32 h0,h1,h2,h3,l0,l1,l2,l3;
  split2(va.x, va.y, h0, l0); split2(va.z, va.w, h1, l1);
  split2(vb.x, vb.y, h2, l2); split2(vb.z, vb.w, h3, l3);
  size_t off = ((((size_t)t * 32 + KT) * 4 + bq) << 10) + ((size_t)lane << 4);
  *(uint4*)(xpl + off)            = make_uint4(h0, h1, h2, h3);
  *(uint4*)(xpl + 13107200 + off) = make_uint4(l0, l1, l2, l3);
}

// stage both planes of one (KT, nt) 1KB slice pair into B dbuf
__device__ __forceinline__ void stageS(
    char* lds, const char* xpl, const char* ringp,
    int t, int pn, int ko, int nt, int bq, int lane)
{
  const int KT = 8 * pn + ko;
  char* dst = lds + BOFF_ + ((pn & 1) << 15) + (ko << 12) + (nt << 11);
  const char *s0, *s1;
  if (KT < 32) {
    size_t o = ((((size_t)t * 32 + KT) * 4 + bq) << 10) + ((size_t)lane << 4);
    s0 = xpl + o;
    s1 = xpl + 13107200 + o;
  } else {
    size_t o = (size_t)t * 524288 + ((((size_t)(KT - 32) * 4) + bq) << 10) + ((size_t)lane << 4);
    s0 = ringp + o;
    s1 = ringp + 262144 + o;
  }
  gl_lds16(s0, dst);
  gl_lds16(s1, dst + 1024);
}

// one MFMA phase: A-lo from LDS (p<10) or regs; B from dbuf[p&1]; 3 split passes
__device__ __forceinline__ void phase_mfma(
    const char* lds, int p, int q, int ntc, int lane,
    const bf16x8* rah, const bf16x8* ral2, f32x16& acc)
{
  const int KT = 8 * p + q;
  bf16x8 al;
  if (p < 10) al = *(const bf16x8*)(lds + ALO_ + (KT << 10) + (lane << 4));
  else        al = ral2[p - 10];
  const char* bbp = lds + BOFF_ + ((p & 1) << 15) + (q << 12) + (ntc << 11);
  bf16x8 bh = *(const bf16x8*)(bbp + (lane << 4));
  bf16x8 bl = *(const bf16x8*)(bbp + 1024 + (lane << 4));
  acc = __builtin_amdgcn_mfma_f32_32x32x16_bf16(rah[p], bh, acc, 0, 0, 0);
  acc = __builtin_amdgcn_mfma_f32_32x32x16_bf16(rah[p], bl, acc, 0, 0, 0);
  acc = __builtin_amdgcn_mfma_f32_32x32x16_bf16(al,     bh, acc, 0, 0, 0);
}

#define VMCNT2 asm volatile("s_waitcnt vmcnt(2)" ::: "memory")
#define VMCNT0 asm volatile("s_waitcnt vmcnt(0)" ::: "memory")
#define SBAR   __builtin_amdgcn_s_barrier()
#define SCHB   __builtin_amdgcn_sched_barrier(0)

// ===== tierS persistent GRU: 32x32x16 MFMA; order H(t)->epilogue->X(t+1)->gridbar
__global__ __launch_bounds__(1024, 4) void gru_mfma6(
    const char* __restrict__ xpl, char* __restrict__ ringp,
    const float* __restrict__ wih, const float* __restrict__ whh,
    const float* __restrict__ bih, const float* __restrict__ bhh,
    float* __restrict__ hq, unsigned* __restrict__ barr)
{
  extern __shared__ char lds[];
  const int tid  = threadIdx.x;
  const int lane = tid & 63;
  const int wv   = __builtin_amdgcn_readfirstlane(tid >> 6);
  const int q    = wv >> 1;            // k-parity 0..7
  const int ntc  = wv & 1;             // n-tile 0..1
  const int bid  = blockIdx.x;
  const int j0   = (bid >> 1) << 3;
  const int bhalf = bid & 1;
  const int bq   = bhalf * 2 + ntc;

  // ---- one-time: A fragments (hi in regs; lo KT0..79 in LDS, KT80..95 regs)
  bf16x8 rah[12], ral2[2];
  {
    const int rrow = lane & 31, g = rrow >> 3, jl_a = rrow & 7, kg_a = lane >> 5;
    const int jA = j0 + jl_a;
    #pragma unroll
    for (int p = 0; p < 12; ++p) {
      const int KT = 8 * p + q;
      const int kb = KT * 16 + kg_a * 8;
      bf16x8 hi8, lo8;
      bool zero = (p <= 3) ? (g == 3) : (g == 2);
      if (zero) {
        #pragma unroll
        for (int e = 0; e < 8; ++e) { hi8[e] = 0; lo8[e] = 0; }
      } else {
        const float* srcp;
        if (p <= 3) srcp = wih + (size_t)(g * H_ + jA) * IN_ + kb;
        else        srcp = whh + (size_t)(((g == 3) ? 2 : g) * H_ + jA) * H_ + (kb - IN_);
        float4 va = *(const float4*)srcp;
        float4 vb = *(const float4*)(srcp + 4);
        float vv[8] = {va.x, va.y, va.z, va.w, vb.x, vb.y, vb.z, vb.w};
        #pragma unroll
        for (int e = 0; e < 8; ++e) {
          uint32 hb = bf16_rne(vv[e]);
          float hf = __builtin_bit_cast(float, hb << 16);
          uint32 lb = bf16_rne(vv[e] - hf);
          hi8[e] = (short)hb; lo8[e] = (short)lb;
        }
      }
      rah[p] = hi8;
      if (p <= 9) {
        if (ntc == 0)
          *(bf16x8*)(lds + ALO_ + (KT << 10) + (lane << 4)) = lo8;
      } else {
        ral2[p - 10] = lo8;
      }
    }
  }

  // epilogue thread mapping (tid<128): b 0..63 x hi 0..1; handles 4 j (jli 0..3)
  const int eb  = tid & 63;
  const int ehi = (tid >> 6) & 1;
  f32x4 bir4 = {0,0,0,0}, biz4 = {0,0,0,0}, bin4 = {0,0,0,0};
  f32x4 bhr4 = {0,0,0,0}, bhz4 = {0,0,0,0}, bhn4 = {0,0,0,0};
  if (tid < 128) {
    const int jb = j0 + ehi * 4;
    bir4 = *(const f32x4*)&bih[jb];
    biz4 = *(const f32x4*)&bih[H_ + jb];
    bin4 = *(const f32x4*)&bih[2 * H_ + jb];
    bhr4 = *(const f32x4*)&bhh[jb];
    bhz4 = *(const f32x4*)&bhh[H_ + jb];
    bhn4 = *(const f32x4*)&bhh[2 * H_ + jb];
  }
  float hp4[4] = {0.f, 0.f, 0.f, 0.f};
  __syncthreads();

  f32x16 acc = {0.f,0.f,0.f,0.f,0.f,0.f,0.f,0.f,0.f,0.f,0.f,0.f,0.f,0.f,0.f,0.f};

  // ---- prologue: X phases of t=0
  stageS(lds, xpl, ringp, 0, 0, q, ntc, bq, lane);
  stageS(lds, xpl, ringp, 0, 1, q, ntc, bq, lane);
  VMCNT2; SBAR; SCHB; phase_mfma(lds, 0, q, ntc, lane, rah, ral2, acc); SCHB; SBAR;
  stageS(lds, xpl, ringp, 0, 2, q, ntc, bq, lane);
  VMCNT2; SBAR; SCHB; phase_mfma(lds, 1, q, ntc, lane, rah, ral2, acc); SCHB; SBAR;
  stageS(lds, xpl, ringp, 0, 3, q, ntc, bq, lane);
  VMCNT2; SBAR; SCHB; phase_mfma(lds, 2, q, ntc, lane, rah, ral2, acc); SCHB; SBAR;
  VMCNT0; SBAR; SCHB; phase_mfma(lds, 3, q, ntc, lane, rah, ral2, acc); SCHB; SBAR;

  for (int t = 0; t < T_; ++t) {
    // ---- H phases (p 4..11) on ring h(t)
    stageS(lds, xpl, ringp, t, 4, q, ntc, bq, lane);
    #pragma unroll
    for (int p = 4; p <= 10; ++p) {
      stageS(lds, xpl, ringp, t, p + 1, q, ntc, bq, lane);
      VMCNT2; SBAR; SCHB;
      phase_mfma(lds, p, q, ntc, lane, rah, ral2, acc);
      SCHB; SBAR;
    }
    VMCNT0; SBAR; SCHB;
    phase_mfma(lds, 11, q, ntc, lane, rah, ral2, acc);
    SCHB; SBAR;

    // ---- epilogue: one-round 64KB dump (both bufs) + b128 reduce + gates
    {
      char* d = lds + BOFF_ + (q << 13) + (ntc << 12) + (lane << 4);
      *(f32x4*)(d)        = (f32x4){acc[0],  acc[1],  acc[2],  acc[3]};
      *(f32x4*)(d + 1024) = (f32x4){acc[4],  acc[5],  acc[6],  acc[7]};
      *(f32x4*)(d + 2048) = (f32x4){acc[8],  acc[9],  acc[10], acc[11]};
      *(f32x4*)(d + 3072) = (f32x4){acc[12], acc[13], acc[14], acc[15]};
    }
    __syncthreads();

    if (tid < 128) {
      const int lane_w = (eb & 31) + (ehi << 5);
      const int bb5 = eb >> 5;
      f32x4 s0 = {0,0,0,0}, s1 = {0,0,0,0}, s2 = {0,0,0,0}, s3 = {0,0,0,0};
      #pragma unroll
      for (int qq = 0; qq < 8; ++qq) {
        const char* base = lds + BOFF_ + (qq << 13) + (bb5 << 12) + (lane_w << 4);
        s0 += *(const f32x4*)(base);
        s1 += *(const f32x4*)(base + 1024);
        s2 += *(const f32x4*)(base + 2048);
        s3 += *(const f32x4*)(base + 3072);
      }
      uint32 hh[4], ll[4];
      float hv4[4];
      #pragma unroll
      for (int jli = 0; jli < 4; ++jli) {
        float rr = sigf(s0[jli] + bir4[jli] + bhr4[jli]);
        float zz = sigf(s1[jli] + biz4[jli] + bhz4[jli]);
        float nn = tanhf(s2[jli] + bin4[jli] + rr * (s3[jli] + bhn4[jli]));
        float hv = (1.f - zz) * nn + zz * hp4[jli];
        hp4[jli] = hv; hv4[jli] = hv;
        uint32 hb = bf16_rne(hv);
        float hf = __builtin_bit_cast(float, hb << 16);
        ll[jli] = bf16_rne(hv - hf);
        hh[jli] = hb;
      }
      u64t HI = (u64t)hh[0] | ((u64t)hh[1] << 16) | ((u64t)hh[2] << 32) | ((u64t)hh[3] << 48);
      u64t LO = (u64t)ll[0] | ((u64t)ll[1] << 16) | ((u64t)ll[2] << 32) | ((u64t)ll[3] << 48);
      const int kg  = (bid >> 1) & 1;
      const int KTh = bid >> 2;
      const int bq2 = bhalf * 2 + (eb >> 5);
      const int lane_f = (eb & 31) + (kg << 5);
      size_t off = ((((size_t)KTh << 2) + bq2) << 10) + ((size_t)lane_f << 4) + ((size_t)ehi << 3);
      char* basep = ringp + (size_t)(t + 1) * 524288;
      st_u64_sc1(basep + off, HI);
      st_u64_sc1(basep + 262144 + off, LO);
      if (t == T_ - 1)
        *(float4*)&hq[(size_t)(bhalf * 64 + eb) * H_ + j0 + 4 * ehi] =
            make_float4(hv4[0], hv4[1], hv4[2], hv4[3]);
    }

    if (t < T_ - 1) {
      // D-barrier: LDS reads of dump done before X staging overwrites bufs.
      asm volatile("s_waitcnt lgkmcnt(0)" ::: "memory");
      SCHB; SBAR;

      acc = (f32x16){0.f,0.f,0.f,0.f,0.f,0.f,0.f,0.f,0.f,0.f,0.f,0.f,0.f,0.f,0.f,0.f};
      // ---- X phases of t+1 (xpl only) before the grid barrier
      stageS(lds, xpl, ringp, t + 1, 0, q, ntc, bq, lane);
      stageS(lds, xpl, ringp, t + 1, 1, q, ntc, bq, lane);
      VMCNT2; SBAR; SCHB; phase_mfma(lds, 0, q, ntc, lane, rah, ral2, acc); SCHB; SBAR;
      stageS(lds, xpl, ringp, t + 1, 2, q, ntc, bq, lane);
      VMCNT2; SBAR; SCHB; phase_mfma(lds, 1, q, ntc, lane, rah, ral2, acc); SCHB; SBAR;
      stageS(lds, xpl, ringp, t + 1, 3, q, ntc, bq, lane);
      VMCNT2; SBAR; SCHB; phase_mfma(lds, 2, q, ntc, lane, rah, ral2, acc); SCHB; SBAR;
      VMCNT0; SBAR; SCHB; phase_mfma(lds, 3, q, ntc, lane, rah, ral2, acc); SCHB; SBAR;

      gridbar(barr + t);
    }
  }
}

// ================= r10 fallback kernel (proven) ==============================
__device__ __forceinline__ int boff(int kt, int nt, int lane) {
  return (((((kt << 3) + nt) << 6) + lane) << 4) ^ ((nt & 3) << 5);
}

__global__ __launch_bounds__(256) void xt_kernel(
    const float* __restrict__ X, float4* __restrict__ XT4)
{
  int idx = blockIdx.x * 256 + threadIdx.x;
  int b  = idx & 127;
  int kq = (idx >> 7) & 127;
  int t  = idx >> 14;
  XT4[idx] = *(const float4*)(X + ((size_t)b * T_ + t) * IN_ + kq * 4);
}

template<bool RING>
__global__ __launch_bounds__(1024, 4) void gru_mfma(
    const float4* __restrict__ XT4, const float* __restrict__ X, int use_xt,
    const float* __restrict__ wih, const float* __restrict__ whh,
    const float* __restrict__ bih, const float* __restrict__ bhh,
    float* __restrict__ ring, unsigned* __restrict__ barr)
{
  extern __shared__ char lds[];
  const int tid  = threadIdx.x;
  const int lane = tid & 63;
  const int wv   = __builtin_amdgcn_readfirstlane(tid >> 6);
  const int nt   = wv & 7;
  const int ktw  = wv >> 3;
  const int j0   = blockIdx.x << 2;

  for (int ii = tid * 2; ii < 24576; ii += 2048) {
    int r = ii / 1536, k = ii - r * 1536;
    int jj = r & 3, g = r >> 2;
    float f0, f1;
    if (k < IN_) {
      if (g == 3) { f0 = 0.f; f1 = 0.f; }
      else {
        const float* p = wih + (size_t)(((g == 2 ? 2 : g) * H_) + j0 + jj) * IN_ + k;
        f0 = p[0]; f1 = p[1];
      }
    } else {
      if (g == 2) { f0 = 0.f; f1 = 0.f; }
      else {
        const float* p = whh + (size_t)(((g == 3 ? 2 : g) * H_) + j0 + jj) * H_ + (k - IN_);
        f0 = p[0]; f1 = p[1];
      }
    }
    uint32 h, l; split2(f0, f1, h, l);
    int KT = k >> 5, k32 = k & 31;
    int ln  = r + ((k32 >> 3) << 4);
    int off = (KT << 10) + (ln << 4) + ((k32 & 7) << 1);
    *(uint32*)(lds + off)         = h;
    *(uint32*)(lds + A_LOF + off) = l;
  }

  const int ejj = tid >> 7, eb = tid & 127;
  float bir = 0.f, biz = 0.f, bin = 0.f, bhr = 0.f, bhz = 0.f, bhn = 0.f;
  if (tid < 512) {
    int j = j0 + ejj;
    bir = bih[j]; biz = bih[H_ + j]; bin = bih[2 * H_ + j];
    bhr = bhh[j]; bhz = bhh[H_ + j]; bhn = bhh[2 * H_ + j];
  }
  __syncthreads();

  const int kq_loc = tid >> 7;
  const int sb     = tid & 127;
  const int s_nt   = sb >> 4;
  const int lane_w = (sb & 15) + ((kq_loc >> 1) << 4);
  const int sub8   = (kq_loc & 1) << 3;

  for (int t = 0; t < T_; ++t) {
    const float4* __restrict__ hp4 =
        (const float4*)ring + (size_t)(RING ? t : (t & 1)) * 32768;
    float* __restrict__ hnf =
        ring + (size_t)(RING ? (t + 1) : ((t + 1) & 1)) * 131072;
    const float4* __restrict__ xt_t = XT4 + (size_t)t * 16384;

    f32x4 acc = {0.f, 0.f, 0.f, 0.f};

    #pragma unroll 1
    for (int c = 0; c < 24; ++c) {
      #pragma unroll
      for (int i = 0; i < 2; ++i) {
        int kqg = (c << 4) + kq_loc + (i << 3);
        float4 v;
        if (kqg < 128) {
          if (use_xt) v = xt_t[kqg * 128 + sb];
          else        v = *(const float4*)(X + ((size_t)sb * T_ + t) * IN_ + (kqg << 2));
        } else {
          v = RING ? hp4[(kqg - 128) * 128 + sb]
                   : ld_h4_sc1(hp4 + (kqg - 128) * 128 + sb);
        }
        uint32 h01, h23, l01, l23;
        split2(v.x, v.y, h01, l01);
        split2(v.z, v.w, h23, l23);
        int bo = boff(i, s_nt, lane_w) + sub8;
        *(uint2*)(lds + BB_HI + bo) = make_uint2(h01, h23);
        *(uint2*)(lds + BB_LO + bo) = make_uint2(l01, l23);
      }
      __syncthreads();
      {
        int KT = (c << 1) + ktw;
        bf16x8 ah = *(const bf16x8*)(lds + (KT << 10) + (lane << 4));
        bf16x8 al = *(const bf16x8*)(lds + A_LOF + (KT << 10) + (lane << 4));
        int bo = boff(ktw, nt, lane);
        bf16x8 bh = *(const bf16x8*)(lds + BB_HI + bo);
        bf16x8 bl = *(const bf16x8*)(lds + BB_LO + bo);
        acc = __builtin_amdgcn_mfma_f32_16x16x32_bf16(ah, bh, acc, 0, 0, 0);
        acc = __builtin_amdgcn_mfma_f32_16x16x32_bf16(ah, bl, acc, 0, 0, 0);
        acc = __builtin_amdgcn_mfma_f32_16x16x32_bf16(al, bh, acc, 0, 0, 0);
      }
      __syncthreads();
    }

    *(f32x4*)(lds + BB_HI + boff(ktw, nt, lane)) = acc;
    __syncthreads();
    if (tid < 512) {
      float sv[4];
      #pragma unroll
      for (int g = 0; g < 4; ++g) {
        int r  = (g << 2) + ejj;
        int lr = (eb & 15) + ((r >> 2) << 4);
        int rg = (r & 3) << 2;
        float v0 = *(const float*)(lds + BB_HI + boff(0, eb >> 4, lr) + rg);
        float v1 = *(const float*)(lds + BB_HI + boff(1, eb >> 4, lr) + rg);
        sv[g] = v0 + v1;
      }
      float rr = sigf(sv[0] + bir + bhr);
      float zz = sigf(sv[1] + biz + bhz);
      float nn = tanhf(sv[2] + bin + rr * (sv[3] + bhn));
      int hidx = ((blockIdx.x * 128 + eb) << 2) + ejj;
      float hpv;
      if (RING) hpv = ((const float*)hp4)[hidx];
      else      hpv = __hip_atomic_load(&((const float*)hp4)[hidx],
                                        __ATOMIC_RELAXED, __HIP_MEMORY_SCOPE_AGENT);
      float hv = (1.f - zz) * nn + zz * hpv;
      __hip_atomic_store(&hnf[hidx], hv, __ATOMIC_RELAXED, __HIP_MEMORY_SCOPE_AGENT);
    }
    gridbar(barr + t);
  }
}

// Final h4T -> hfin[b][k]  (fallback path only)
__global__ __launch_bounds__(256) void hfin_kernel(
    const float* __restrict__ h4, float* __restrict__ out)
{
  int idx = blockIdx.x * 256 + threadIdx.x;
  int b = idx >> 10, k = idx & 1023;
  out[idx] = h4[(((k >> 2) * 128 + b) << 2) + (k & 3)];
}

// Gating GRUs: one wave per batch, gate-per-lane, all state in regs.
__global__ __launch_bounds__(64, 1) void gating_kernel(
    const float* __restrict__ X,
    const float* __restrict__ gwih0, const float* __restrict__ gwhh0,
    const float* __restrict__ gbih0, const float* __restrict__ gbhh0,
    const float* __restrict__ gwih1, const float* __restrict__ gwhh1,
    const float* __restrict__ gbih1, const float* __restrict__ gbhh1,
    float* __restrict__ omega)
{
  const int b = blockIdx.x;
  const int g = threadIdx.x;
  const int u = g & 7;
  float wi0[GIN_] = {}, wh0[GH_] = {}, wi1[GH_] = {}, wh1[GH_] = {};
  float bi0 = 0.f, bh0 = 0.f, bi1 = 0.f, bh1 = 0.f;
  if (g < 3 * GH_) {
    #pragma unroll
    for (int i = 0; i < GIN_; ++i) wi0[i] = gwih0[g * GIN_ + i];
    #pragma unroll
    for (int k = 0; k < GH_; ++k) { wh0[k] = gwhh0[g * GH_ + k]; wi1[k] = gwih1[g * GH_ + k]; wh1[k] = gwhh1[g * GH_ + k]; }
    bi0 = gbih0[g]; bh0 = gbhh0[g]; bi1 = gbih1[g]; bh1 = gbhh1[g];
  }
  float h0[GH_] = {}, h1[GH_] = {};
  for (int t = 0; t < T_; ++t) {
    float xt[GIN_];
    #pragma unroll
    for (int i = 0; i < GIN_; ++i) xt[i] = X[((size_t)b * T_ + t) * IN_ + (IN_ - GIN_) + i];
    float px = bi0, ph = bh0;
    #pragma unroll
    for (int i = 0; i < GIN_; ++i) px = fmaf(xt[i], wi0[i], px);
    #pragma unroll
    for (int k = 0; k < GH_; ++k) ph = fmaf(h0[k], wh0[k], ph);
    float s = px + ph;
    float s_r = __shfl(s, u);
    float s_z = __shfl(s, 8 + u);
    float nval = tanhf(px + sigf(s_r) * ph);
    float zval = sigf(s_z);
    float hnew = (1.f - zval) * nval + zval * h0[u];
    #pragma unroll
    for (int k = 0; k < GH_; ++k) h0[k] = __shfl(hnew, 16 + k);
    float px1 = bi1, ph1 = bh1;
    #pragma unroll
    for (int k = 0; k < GH_; ++k) px1 = fmaf(h0[k], wi1[k], px1);
    #pragma unroll
    for (int k = 0; k < GH_; ++k) ph1 = fmaf(h1[k], wh1[k], ph1);
    float s1 = px1 + ph1;
    float s1r = __shfl(s1, u);
    float s1z = __shfl(s1, 8 + u);
    float n1 = tanhf(px1 + sigf(s1r) * ph1);
    float z1 = sigf(s1z);
    float h1new = (1.f - z1) * n1 + z1 * h1[u];
    #pragma unroll
    for (int k = 0; k < GH_; ++k) h1[k] = __shfl(h1new, 16 + k);
  }
  if (g < GH_) {
    float m = h1[0];
    #pragma unroll
    for (int k = 1; k < GH_; ++k) m = fmaxf(m, h1[k]);
    float sum = 0.f;
    #pragma unroll
    for (int k = 0; k < GH_; ++k) sum += expf(h1[k] - m);
    omega[b * GH_ + g] = expf(h1[g] - m) / sum;
  }
}

// MoE layer
__global__ __launch_bounds__(256, 2) void moe_kernel(
    const float* __restrict__ in, const float* __restrict__ w,
    const float* __restrict__ bias, const float* __restrict__ omega,
    float* __restrict__ out, int K, int act)
{
  __shared__ float4 lin4[64 * 32];
  __shared__ float  ldsw[E_ * 4 * 128];
  const int tid  = threadIdx.x;
  const int bh   = blockIdx.x & 1;
  const int jt   = blockIdx.x >> 1;
  const int wv   = tid >> 6;
  const int lane = tid & 63;
  const int j0   = jt * 4;
  const int j    = __builtin_amdgcn_readfirstlane(j0 + wv);
  const int b    = bh * 64 + lane;

  float acc[E_] = {0.f,0.f,0.f,0.f,0.f,0.f,0.f,0.f};
  const float4* row4 = &lin4[lane * 32];
  const int nch = K / 128;

  for (int c = 0; c < nch; ++c) {
    __syncthreads();
    const int k0 = c * 128;
    #pragma unroll
    for (int it = 0; it < 8; ++it) {
      int f = it * 256 + tid;
      int bb = f >> 5, qq = f & 31;
      float4 v = *(const float4*)(in + (size_t)(bh * 64 + bb) * K + k0 + qq * 4);
      lin4[bb * 32 + ((qq & 24) | ((qq ^ bb) & 7))] = v;
    }
    #pragma unroll
    for (int it = 0; it < 4; ++it) {
      int f = it * 256 + tid;
      int e = f >> 7, k = f & 127;
      float4 v = *(const float4*)(w + ((size_t)e * K + k0 + k) * HH_ + j0);
      ldsw[(e * 4 + 0) * 128 + k] = v.x;
      ldsw[(e * 4 + 1) * 128 + k] = v.y;
      ldsw[(e * 4 + 2) * 128 + k] = v.z;
      ldsw[(e * 4 + 3) * 128 + k] = v.w;
    }
    __syncthreads();
    #pragma unroll 2
    for (int qq = 0; qq < 32; ++qq) {
      float4 xv = row4[(qq & 24) | ((qq ^ lane) & 7)];
      #pragma unroll
      for (int e = 0; e < E_; ++e) {
        const float4 wq = *(const float4*)&ldsw[(e * 4 + wv) * 128 + 4 * qq];
        acc[e] = fmaf(xv.x, wq.x, acc[e]);
        acc[e] = fmaf(xv.y, wq.y, acc[e]);
        acc[e] = fmaf(xv.z, wq.z, acc[e]);
        acc[e] = fmaf(xv.w, wq.w, acc[e]);
      }
    }
  }

  float om[E_];
  #pragma unroll
  for (int e = 0; e < E_; ++e) om[e] = omega[b * E_ + e];
  float v = 0.f;
  #pragma unroll
  for (int e = 0; e < E_; ++e) v = fmaf(om[e], acc[e] + bias[e * HH_ + j], v);
  if (act == 0) v = (v > 0.f) ? v : expm1f(v);
  else          v = fminf(fmaxf(v, 0.f), 1.f);
  out[(size_t)b * HH_ + j] = v;
}

extern "C" void kernel_launch(void* const* d_in, const int* in_sizes, int n_in,
                              void* d_out, int out_size, void* d_ws, size_t ws_size,
                              hipStream_t stream) {
  (void)in_sizes; (void)n_in; (void)out_size;
  const float* X     = (const float*)d_in[0];
  const float* gwih0 = (const float*)d_in[1];
  const float* gwhh0 = (const float*)d_in[2];
  const float* gbih0 = (const float*)d_in[3];
  const float* gbhh0 = (const float*)d_in[4];
  const float* gwih1 = (const float*)d_in[5];
  const float* gwhh1 = (const float*)d_in[6];
  const float* gbih1 = (const float*)d_in[7];
  const float* gbhh1 = (const float*)d_in[8];
  const float* mwih  = (const float*)d_in[9];
  const float* mwhh  = (const float*)d_in[10];
  const float* mbih  = (const float*)d_in[11];
  const float* mbhh  = (const float*)d_in[12];
  const float* w1    = (const float*)d_in[13];
  const float* b1    = (const float*)d_in[14];
  const float* w2    = (const float*)d_in[15];
  const float* b2    = (const float*)d_in[16];
  const float* w3    = (const float*)d_in[17];
  const float* b3    = (const float*)d_in[18];

  const size_t HBUF = (size_t)B_ * H_;
  size_t tierS_f = 256 + HBUF + 101 * HBUF + 1024 + 2 * (size_t)B_ * HH_ + HBUF + 6553600;
  const size_t XTF = (size_t)T_ * IN_ * B_;
  size_t ringA = 256 + (size_t)(T_ + 1) * HBUF + HBUF + 1024 + 2 * (size_t)B_ * HH_ + XTF;
  size_t ringB = 256 + 2 * HBUF + HBUF + 1024 + 2 * (size_t)B_ * HH_ + XTF;

  float* ws = (float*)d_ws;

  if (ws_size >= tierS_f * sizeof(float)) {
    unsigned* barr = (unsigned*)ws;
    float* hq    = ws + 256;
    float* ringp = hq + HBUF;
    float* om    = ringp + 101 * HBUF;
    float* a1    = om + 1024;
    float* a2    = a1 + (size_t)B_ * HH_;
    float* xpl   = a2 + (size_t)B_ * HH_ + HBUF;   // (hfin slot unused)

    (void)hipMemsetAsync(d_ws, 0, 256 * sizeof(float), stream);
    (void)hipMemsetAsync(ringp, 0, 524288, stream);
    (void)hipFuncSetAttribute((const void*)gru_mfma6,
                        hipFuncAttributeMaxDynamicSharedMemorySize, LDSZ5);

    gating_kernel<<<128, 64, 0, stream>>>(X, gwih0, gwhh0, gbih0, gbhh0,
                                          gwih1, gwhh1, gbih1, gbhh1, om);
    xsplit_kernel<<<3200, 256, 0, stream>>>(X, (char*)xpl);
    gru_mfma6<<<256, 1024, LDSZ5, stream>>>((const char*)xpl, (char*)ringp,
        mwih, mwhh, mbih, mbhh, hq, barr);
    moe_kernel<<<256, 256, 0, stream>>>(hq, w1, b1, om, a1, H_, 0);
    moe_kernel<<<256, 256, 0, stream>>>(a1, w2, b2, om, a2, HH_, 0);
    moe_kernel<<<256, 256, 0, stream>>>(a2, w3, b3, om, (float*)d_out, HH_, 1);
    return;
  }

  // -------- fallback: r10 proven path --------
  int tierA   = ws_size >= ringA * sizeof(float);
  int use_xt  = tierA || (ws_size >= ringB * sizeof(float));
  int R       = tierA ? (T_ + 1) : 2;

  unsigned* barr = (unsigned*)ws;
  float* ring = ws + 256;
  float* hfin = ring + (size_t)R * HBUF;
  float* om   = hfin + HBUF;
  float* a1   = om + 1024;
  float* a2   = a1 + (size_t)B_ * HH_;
  float* XT   = a2 + (size_t)B_ * HH_;

  (void)hipMemsetAsync(d_ws, 0, (256 + HBUF) * sizeof(float), stream);
  (void)hipFuncSetAttribute((const void*)gru_mfma<true>,
                      hipFuncAttributeMaxDynamicSharedMemorySize, LDSZF);
  (void)hipFuncSetAttribute((const void*)gru_mfma<false>,
                      hipFuncAttributeMaxDynamicSharedMemorySize, LDSZF);

  gating_kernel<<<128, 64, 0, stream>>>(X, gwih0, gwhh0, gbih0, gbhh0,
                                        gwih1, gwhh1, gbih1, gbhh1, om);
  if (use_xt)
    xt_kernel<<<(T_ * 128 * 128) / 256, 256, 0, stream>>>(X, (float4*)XT);

  if (tierA)
    gru_mfma<true><<<256, 1024, LDSZF, stream>>>((const float4*)XT, X, use_xt,
        mwih, mwhh, mbih, mbhh, ring, barr);
  else
    gru_mfma<false><<<256, 1024, LDSZF, stream>>>((const float4*)XT, X, use_xt,
        mwih, mwhh, mbih, mbhh, ring, barr);

  const float* hlast = ring + (size_t)(tierA ? T_ : (T_ & 1)) * HBUF;
  hfin_kernel<<<512, 256, 0, stream>>>(hlast, hfin);
  moe_kernel<<<256, 256, 0, stream>>>(hfin, w1, b1, om, a1, H_, 0);
  moe_kernel<<<256, 256, 0, stream>>>(a1, w2, b2, om, a2, HH_, 0);
  moe_kernel<<<256, 256, 0, stream>>>(a2, w3, b3, om, (float*)d_out, HH_, 1);
}